// Round 3
// baseline (35.248 us; speedup 1.0000x reference)
//
#include <hip/hip_runtime.h>
#include <math.h>

#define N_NODES 10000
#define N_REL   500
#define H       128
#define L       128

#define TN   80     // n-tile (125 * 80 = 10000 exactly)
#define TL   64     // l-tile
#define NBX  125    // n-blocks
#define PADF 2100   // pad LDS past 80 KB -> exactly 1 block/CU

__device__ __forceinline__ float waveReduceSum(float v) {
    #pragma unroll
    for (int m = 1; m < 64; m <<= 1) v += __shfl_xor(v, m, 64);
    return v;
}

__device__ __forceinline__ void gload16(const float* g, float* l) {
    __builtin_amdgcn_global_load_lds((const __attribute__((address_space(1))) void*)g,
                                     (__attribute__((address_space(3))) void*)l, 16, 0, 0);
}

// --- kernel A: per-node inverse norms (blocks 0..2499) + query rows (2500..2531)
__global__ __launch_bounds__(256) void k_prep(const float* __restrict__ node,
                                              const float* __restrict__ rel,
                                              const int* __restrict__ eidx,
                                              const int* __restrict__ ridx,
                                              float* __restrict__ invn,
                                              float* __restrict__ query) {
    int wave = threadIdx.x >> 6;
    int lane = threadIdx.x & 63;
    if (blockIdx.x < 2500) {
        int row = blockIdx.x * 4 + wave;            // < 10000 always
        float2 v = *reinterpret_cast<const float2*>(node + row * H + lane * 2);
        float ss = waveReduceSum(v.x * v.x + v.y * v.y);
        if (lane == 0) invn[row] = 1.0f / fmaxf(sqrtf(ss), 1e-12f);
    } else {
        int l = (blockIdx.x - 2500) * 4 + wave;     // < 128 always
        int ei = eidx[l], ri = ridx[l];
        float2 e = *reinterpret_cast<const float2*>(node + ei * H + lane * 2);
        float inve = 1.0f / fmaxf(sqrtf(waveReduceSum(e.x * e.x + e.y * e.y)), 1e-12f);
        float2 r = *reinterpret_cast<const float2*>(rel + ri * H + lane * 2);
        float invr = 1.0f / fmaxf(sqrtf(waveReduceSum(r.x * r.x + r.y * r.y)), 1e-12f);
        float2 q;
        q.x = e.x * inve + r.x * invr;
        q.y = e.y * inve + r.y * invr;
        *reinterpret_cast<float2*>(query + l * H + lane * 2) = q;
    }
}

// --- kernel B: 64x80 tile of exp(L1-dist) + per-row partial sums -----------
// es/qs staged via global_load_lds with source pre-swizzle g(row)=((row>>2)&7)<<2
// stored[row][c] = src[row][c ^ g(row)]; read [row][h ^ g(row)] to get src[row][h]
__global__ __launch_bounds__(256) void k_dist(const float* __restrict__ node,
                                              const float* __restrict__ invn,
                                              const float* __restrict__ query,
                                              float* __restrict__ out,
                                              float* __restrict__ psum) {
    __shared__ float es[TN * H + PADF];   // [n][h] swizzled content, later scaled
    __shared__ float qs[TL * H];          // [l][h] swizzled content
    __shared__ float invs[TN];

    const int tid  = threadIdx.x;
    const int wav  = tid >> 6;
    const int lane = tid & 63;
    const int nb   = blockIdx.x * TN;     // multiple of 80, nb+79 <= 9999
    const int lb   = blockIdx.y * TL;

    if (tid < TN) invs[tid] = invn[nb + tid];

    {
        const int rl = lane >> 5;             // 0/1: row within instr
        const int c0 = (lane & 31) << 2;      // h-offset 0..124
        // es: 80 rows, 20/wave, 2 rows per instr
        #pragma unroll
        for (int k = 0; k < 10; ++k) {
            int row = wav * 20 + k * 2 + rl;
            int g = ((row >> 2) & 7) << 2;
            gload16(node + (size_t)(nb + row) * H + (c0 ^ g),
                    &es[(wav * 20 + k * 2) * H]);
        }
        // qs: 64 rows, 16/wave
        #pragma unroll
        for (int k = 0; k < 8; ++k) {
            int row = wav * 16 + k * 2 + rl;
            int g = ((row >> 2) & 7) << 2;
            gload16(query + (size_t)(lb + row) * H + (c0 ^ g),
                    &qs[(wav * 16 + k * 2) * H]);
        }
    }
    __syncthreads();

    // rescale es rows by invs[n] in place (linear, conflict-free; swizzle-agnostic)
    #pragma unroll
    for (int k = 0; k < 10; ++k) {
        int d4 = tid + (k << 8);              // float4 idx < 2560
        float s = invs[d4 >> 5];
        float4* p = reinterpret_cast<float4*>(es) + d4;
        float4 v = *p;
        v.x *= s; v.y *= s; v.z *= s; v.w *= s;
        *p = v;
    }
    __syncthreads();

    const int tl = tid >> 4;                  // 16 groups x 4 l-rows
    const int tn = tid & 15;                  // 16 groups x 5 n-cols
    const int l0 = tl * 4;
    const int n0 = tn * 5;
    const int gq = (tl & 7) << 2;
    int ge[5];
    #pragma unroll
    for (int j = 0; j < 5; ++j) ge[j] = (((n0 + j) >> 2) & 7) << 2;

    float acc[4][5] = {};

    #pragma unroll 4
    for (int h4 = 0; h4 < 32; ++h4) {
        const int h = h4 << 2;
        float4 qf[4], ef[5];
        #pragma unroll
        for (int i = 0; i < 4; ++i)
            qf[i] = *reinterpret_cast<const float4*>(&qs[(l0 + i) * H + (h ^ gq)]);
        #pragma unroll
        for (int j = 0; j < 5; ++j)
            ef[j] = *reinterpret_cast<const float4*>(&es[(n0 + j) * H + (h ^ ge[j])]);
        #pragma unroll
        for (int i = 0; i < 4; ++i)
            #pragma unroll
            for (int j = 0; j < 5; ++j)
                acc[i][j] += fabsf(qf[i].x - ef[j].x) + fabsf(qf[i].y - ef[j].y)
                           + fabsf(qf[i].z - ef[j].z) + fabsf(qf[i].w - ef[j].w);
    }

    // epilogue: exp (no max needed: dist <= ~34 -> exp <= 6e14, f32-safe),
    // per-row partial sum over this block's 80 columns
    #pragma unroll
    for (int i = 0; i < 4; ++i) {
        int l = lb + l0 + i;
        float rs = 0.f;
        #pragma unroll
        for (int j = 0; j < 5; ++j) {
            float p = expf(acc[i][j]);
            rs += p;
            out[(size_t)l * N_NODES + nb + n0 + j] = p;
        }
        #pragma unroll
        for (int s = 1; s < 16; s <<= 1) rs += __shfl_xor(rs, s, 64);
        if (tn == 0) psum[l * NBX + blockIdx.x] = rs;
    }
}

// --- kernel C: finish softmax: per-row sum of 125 partials, scale ----------
__global__ __launch_bounds__(256) void k_finish(float* __restrict__ out,
                                                const float* __restrict__ psum) {
    __shared__ float red[4];
    int l = blockIdx.y;
    int tid = threadIdx.x;
    float s = (tid < NBX) ? psum[l * NBX + tid] : 0.f;
    #pragma unroll
    for (int m = 1; m < 64; m <<= 1) s += __shfl_xor(s, m, 64);
    if ((tid & 63) == 0) red[tid >> 6] = s;
    __syncthreads();
    float inv = 1.0f / (red[0] + red[1] + red[2] + red[3]);

    int n4 = blockIdx.x * 256 + tid;          // float4 idx within row (<2500)
    if (n4 < 2500) {
        float4* o = reinterpret_cast<float4*>(out) + (size_t)l * 2500 + n4;
        float4 v = *o;
        v.x *= inv; v.y *= inv; v.z *= inv; v.w *= inv;
        *o = v;
    }
}

extern "C" void kernel_launch(void* const* d_in, const int* in_sizes, int n_in,
                              void* d_out, int out_size, void* d_ws, size_t ws_size,
                              hipStream_t stream) {
    const float* node = (const float*)d_in[0];
    const float* rel  = (const float*)d_in[1];
    const int*   eidx = (const int*)d_in[2];
    const int*   ridx = (const int*)d_in[3];
    float* out = (float*)d_out;

    float* invn  = (float*)d_ws;              // 10000 floats
    float* query = (float*)d_ws + 10240;      // 16384 floats
    float* psum  = (float*)d_ws + 26624;      // 128*125 = 16000 floats

    k_prep<<<2532, 256, 0, stream>>>(node, rel, eidx, ridx, invn, query);

    dim3 gridB(NBX, L / TL);                  // 125 x 2 = 250 blocks, 1/CU
    k_dist<<<gridB, 256, 0, stream>>>(node, invn, query, out, psum);

    dim3 gridC((2500 + 255) / 256, L);        // 10 x 128
    k_finish<<<gridC, 256, 0, stream>>>(out, psum);
}

// Round 4
// 34.954 us; speedup vs baseline: 1.0084x; 1.0084x over previous
//
#include <hip/hip_runtime.h>
#include <math.h>

#define N_NODES 10000
#define N_REL   500
#define H       128
#define L       128

#define TN    16     // n-tile: 625 * 16 = 10000 exactly
#define NBLK  625    // n-blocks = grid size of k_main

__device__ __forceinline__ float waveReduceSum(float v) {
    #pragma unroll
    for (int m = 1; m < 64; m <<= 1) v += __shfl_xor(v, m, 64);
    return v;
}

__device__ __forceinline__ void gload16(const float* g, float* l) {
    __builtin_amdgcn_global_load_lds((const __attribute__((address_space(1))) void*)g,
                                     (__attribute__((address_space(3))) void*)l, 16, 0, 0);
}

// --- kernel A: query rows = norm(node[ent]) + norm(rel[rel]) ---------------
// 32 blocks x 4 waves, one wave per l-row
__global__ __launch_bounds__(256) void k_prep(const float* __restrict__ node,
                                              const float* __restrict__ rel,
                                              const int* __restrict__ eidx,
                                              const int* __restrict__ ridx,
                                              float* __restrict__ query) {
    int wav  = threadIdx.x >> 6;
    int lane = threadIdx.x & 63;
    int l = blockIdx.x * 4 + wav;                    // 0..127
    int ei = eidx[l], ri = ridx[l];
    float2 e = *reinterpret_cast<const float2*>(node + ei * H + lane * 2);
    float inve = 1.0f / fmaxf(sqrtf(waveReduceSum(e.x * e.x + e.y * e.y)), 1e-12f);
    float2 r = *reinterpret_cast<const float2*>(rel + ri * H + lane * 2);
    float invr = 1.0f / fmaxf(sqrtf(waveReduceSum(r.x * r.x + r.y * r.y)), 1e-12f);
    float2 q;
    q.x = e.x * inve + r.x * invr;
    q.y = e.y * inve + r.y * invr;
    *reinterpret_cast<float2*>(query + l * H + lane * 2) = q;
}

// --- kernel B: 128 x 16 tile of exp(L1-dist) + per-row partial sums --------
// qs swizzle g_q(row) = ((row>>2)&7)<<2 ; es swizzle g_e(row) = ((row>>1)&7)<<2
// stored[row][c] = src[row][c ^ g(row)]; logical h lives at [row][h ^ g(row)]
// threads: tl = tid>>3 (32 l-groups x 4 rows), tn = tid&7 (8 n-groups x 2 cols)
// -> q reads: 8 distinct addrs/wave, banks spread by gq  (conflict-free, 8-way bcast)
// -> e reads: 8 distinct addrs/wave, banks spread by ge  (conflict-free, 8-way bcast)
__global__ __launch_bounds__(256) void k_main(const float* __restrict__ node,
                                              const float* __restrict__ query,
                                              float* __restrict__ out,
                                              float* __restrict__ psum) {
    __shared__ float qs[L * H];      // 64 KB
    __shared__ float es[TN * H];     // 8 KB
    __shared__ float invs[TN];

    const int tid  = threadIdx.x;
    const int wav  = tid >> 6;
    const int lane = tid & 63;
    const int nb   = blockIdx.x * TN;          // 0..9984, no bounds checks needed

    // ---- stage (global_load_lds, 2 rows of 512B per instruction) ----
    {
        const int c0   = (lane & 31) << 2;     // float offset 0..124 within row
        const int roff = lane >> 5;            // 0/1
        const int rq = wav * 32;
        #pragma unroll
        for (int k = 0; k < 16; ++k) {
            int r = rq + k * 2;
            int row = r + roff;
            int g = ((row >> 2) & 7) << 2;
            gload16(query + row * H + (c0 ^ g), &qs[r * H]);
        }
        const int re = wav * 4;
        #pragma unroll
        for (int k = 0; k < 2; ++k) {
            int r = re + k * 2;
            int row = r + roff;
            int g = ((row >> 1) & 7) << 2;
            gload16(node + (size_t)(nb + row) * H + (c0 ^ g), &es[r * H]);
        }
    }
    __syncthreads();

    // ---- in-block inverse norms of the 16 es rows (permutation-invariant) ----
    if (tid < 128) {
        int row = tid >> 3, seg = tid & 7;
        const float4* p = reinterpret_cast<const float4*>(es + row * H + seg * 16);
        float ss = 0.f;
        #pragma unroll
        for (int u = 0; u < 4; ++u) {
            float4 v = p[u];
            ss += v.x * v.x + v.y * v.y + v.z * v.z + v.w * v.w;
        }
        #pragma unroll
        for (int m = 1; m < 8; m <<= 1) ss += __shfl_xor(ss, m, 64);
        if (seg == 0) invs[row] = 1.0f / fmaxf(sqrtf(ss), 1e-12f);
    }
    __syncthreads();

    // ---- scale es rows in place ----
    #pragma unroll
    for (int k = 0; k < 2; ++k) {
        int d4 = tid + (k << 8);               // float4 idx 0..511
        float s = invs[d4 >> 5];
        float4* p = reinterpret_cast<float4*>(es) + d4;
        float4 v = *p;
        v.x *= s; v.y *= s; v.z *= s; v.w *= s;
        *p = v;
    }
    __syncthreads();

    // ---- compute: 4l x 2n per thread ----
    const int tl = tid >> 3;                   // 0..31
    const int tn = tid & 7;                    // 0..7
    const int gq = (tl & 7) << 2;              // (4tl+i)>>2 == tl for i<4
    const int ge = tn << 2;                    // (2tn+j)>>1 == tn for j<2
    const float* qb = qs + tl * (4 * H);       // 4 consecutive rows
    const float* eb = es + tn * (2 * H);       // 2 consecutive rows

    float acc[4][2] = {};

    #pragma unroll 8
    for (int h4 = 0; h4 < 32; ++h4) {
        const int h = h4 << 2;
        const int tq = h ^ gq;
        const int te = h ^ ge;
        float4 q0 = *reinterpret_cast<const float4*>(qb + tq);
        float4 q1 = *reinterpret_cast<const float4*>(qb + H + tq);
        float4 q2 = *reinterpret_cast<const float4*>(qb + 2 * H + tq);
        float4 q3 = *reinterpret_cast<const float4*>(qb + 3 * H + tq);
        float4 e0 = *reinterpret_cast<const float4*>(eb + te);
        float4 e1 = *reinterpret_cast<const float4*>(eb + H + te);
        float4 qa[4] = {q0, q1, q2, q3};
        #pragma unroll
        for (int i = 0; i < 4; ++i) {
            acc[i][0] += fabsf(qa[i].x - e0.x) + fabsf(qa[i].y - e0.y)
                       + fabsf(qa[i].z - e0.z) + fabsf(qa[i].w - e0.w);
            acc[i][1] += fabsf(qa[i].x - e1.x) + fabsf(qa[i].y - e1.y)
                       + fabsf(qa[i].z - e1.z) + fabsf(qa[i].w - e1.w);
        }
    }

    // ---- epilogue: exp (no max subtraction; dist<=~40 -> f32-safe), ----
    // ---- store, per-row partial sum over this block's 16 columns    ----
    #pragma unroll
    for (int i = 0; i < 4; ++i) {
        int l = tl * 4 + i;                    // global row (TL = all 128)
        float p0 = expf(acc[i][0]);
        float p1 = expf(acc[i][1]);
        *reinterpret_cast<float2*>(out + (size_t)l * N_NODES + nb + tn * 2) =
            make_float2(p0, p1);
        float rs = p0 + p1;
        rs += __shfl_xor(rs, 1, 64);
        rs += __shfl_xor(rs, 2, 64);
        rs += __shfl_xor(rs, 4, 64);           // sums the 8 tn-lanes of this tl
        if (tn == 0) psum[l * NBLK + blockIdx.x] = rs;
    }
}

// --- kernel C: finish softmax: per-row sum of 625 partials, scale ----------
__global__ __launch_bounds__(256) void k_finish(float* __restrict__ out,
                                                const float* __restrict__ psum) {
    __shared__ float red[4];
    int l = blockIdx.y;
    int tid = threadIdx.x;
    const float* ps = psum + l * NBLK;
    float s = ps[tid] + ps[tid + 256] + (tid < 113 ? ps[tid + 512] : 0.f);
    #pragma unroll
    for (int m = 1; m < 64; m <<= 1) s += __shfl_xor(s, m, 64);
    if ((tid & 63) == 0) red[tid >> 6] = s;
    __syncthreads();
    float inv = 1.0f / (red[0] + red[1] + red[2] + red[3]);

    int n4 = blockIdx.x * 256 + tid;           // float4 idx within row (<2500)
    if (n4 < 2500) {
        float4* o = reinterpret_cast<float4*>(out) + (size_t)l * 2500 + n4;
        float4 v = *o;
        v.x *= inv; v.y *= inv; v.z *= inv; v.w *= inv;
        *o = v;
    }
}

extern "C" void kernel_launch(void* const* d_in, const int* in_sizes, int n_in,
                              void* d_out, int out_size, void* d_ws, size_t ws_size,
                              hipStream_t stream) {
    const float* node = (const float*)d_in[0];
    const float* rel  = (const float*)d_in[1];
    const int*   eidx = (const int*)d_in[2];
    const int*   ridx = (const int*)d_in[3];
    float* out = (float*)d_out;

    float* query = (float*)d_ws;              // 128*128 = 16384 floats
    float* psum  = (float*)d_ws + 16384;      // 128*625 = 80000 floats

    k_prep<<<32, 256, 0, stream>>>(node, rel, eidx, ridx, query);
    k_main<<<NBLK, 256, 0, stream>>>(node, query, out, psum);

    dim3 gridC((2500 + 255) / 256, L);        // 10 x 128
    k_finish<<<gridC, 256, 0, stream>>>(out, psum);
}

// Round 5
// 27.184 us; speedup vs baseline: 1.2966x; 1.2858x over previous
//
#include <hip/hip_runtime.h>
#include <math.h>

#define N_NODES 10000
#define N_REL   500
#define H       128
#define L       128

#define TN    20     // n-tile: 500 * 20 = 10000 exactly
#define NBLK  500    // n-blocks = grid of k_main

__device__ __forceinline__ float waveReduceSum(float v) {
    #pragma unroll
    for (int m = 1; m < 64; m <<= 1) v += __shfl_xor(v, m, 64);
    return v;
}

__device__ __forceinline__ void gload16(const float* g, float* l) {
    __builtin_amdgcn_global_load_lds((const __attribute__((address_space(1))) void*)g,
                                     (__attribute__((address_space(3))) void*)l, 16, 0, 0);
}

// --- kernel A: query rows = norm(node[ent]) + norm(rel[rel]) ---------------
__global__ __launch_bounds__(256) void k_prep(const float* __restrict__ node,
                                              const float* __restrict__ rel,
                                              const int* __restrict__ eidx,
                                              const int* __restrict__ ridx,
                                              float* __restrict__ query) {
    int wav  = threadIdx.x >> 6;
    int lane = threadIdx.x & 63;
    int l = blockIdx.x * 4 + wav;                    // 0..127
    int ei = eidx[l], ri = ridx[l];
    float2 e = *reinterpret_cast<const float2*>(node + ei * H + lane * 2);
    float inve = 1.0f / fmaxf(sqrtf(waveReduceSum(e.x * e.x + e.y * e.y)), 1e-12f);
    float2 r = *reinterpret_cast<const float2*>(rel + ri * H + lane * 2);
    float invr = 1.0f / fmaxf(sqrtf(waveReduceSum(r.x * r.x + r.y * r.y)), 1e-12f);
    float2 q;
    q.x = e.x * inve + r.x * invr;
    q.y = e.y * inve + r.y * invr;
    *reinterpret_cast<float2*>(query + l * H + lane * 2) = q;
}

// --- kernel B: 128 x 20 tile; waves split h (4 x 32); lane tile 8l x 5n ----
// qs/es stored with content swizzle stored[row][c] = src[row][c ^ ((row&7)<<2)]
// l-rows interleaved: l = grp + 16*i  (grp = (lane>>2), i<8)  -> l&7 = grp&7
// n interleaved:      n = nl + 4*j    (nl = lane&3, j<5)
__global__ __launch_bounds__(256, 2) void k_main(const float* __restrict__ node,
                                                 const float* __restrict__ query,
                                                 float* __restrict__ out,
                                                 float* __restrict__ psum) {
    __shared__ union {
        float qs[L * H];            // 64 KB  (chunk-loop phase)
        float red[4][128][21];      // 42 KB  (epilogue phase, aliases qs)
    } u;
    __shared__ float es[TN * H];    // 10 KB
    __shared__ float invs[TN];

    const int tid  = threadIdx.x;
    const int w    = tid >> 6;          // wave = h-segment (32 h each)
    const int lane = tid & 63;
    const int grp  = lane >> 2;         // 0..15
    const int nl   = lane & 3;          // 0..3
    const int nb   = blockIdx.x * TN;   // exact, no bounds checks

    // ---- stage via global_load_lds (pre-swizzled source) ----
    {
        const int c0   = (lane & 31) << 2;
        const int roff = lane >> 5;
        const int rq   = w * 32;
        #pragma unroll
        for (int k = 0; k < 16; ++k) {
            int r = rq + k * 2;
            int row = r + roff;
            int g = (row & 7) << 2;
            gload16(query + row * H + (c0 ^ g), &u.qs[r * H]);
        }
        #pragma unroll
        for (int k = 0; k < 10; ++k) {
            if ((k & 3) == w) {
                int r = k * 2;
                int row = r + roff;
                int g = (row & 7) << 2;
                gload16(node + (size_t)(nb + row) * H + (c0 ^ g), &es[r * H]);
            }
        }
    }
    __syncthreads();

    // ---- in-block inverse norms of the 20 es rows (swizzle-invariant) ----
    if (tid < 8 * TN) {
        int row = tid >> 3, seg = tid & 7;
        const float4* p = reinterpret_cast<const float4*>(es + row * H + seg * 16);
        float ss = 0.f;
        #pragma unroll
        for (int u2 = 0; u2 < 4; ++u2) {
            float4 v = p[u2];
            ss += v.x * v.x + v.y * v.y + v.z * v.z + v.w * v.w;
        }
        #pragma unroll
        for (int m = 1; m < 8; m <<= 1) ss += __shfl_xor(ss, m, 64);
        if (seg == 0) invs[row] = 1.0f / fmaxf(sqrtf(ss), 1e-12f);
    }
    __syncthreads();

    // ---- scale es rows in place (640 float4) ----
    #pragma unroll
    for (int k = 0; k < 3; ++k) {
        int d4 = tid + (k << 8);
        if (d4 < TN * 32) {
            float s = invs[d4 >> 5];
            float4* p = reinterpret_cast<float4*>(es) + d4;
            float4 v = *p;
            v.x *= s; v.y *= s; v.z *= s; v.w *= s;
            *p = v;
        }
    }
    __syncthreads();

    // ---- main loop: 8 chunks of 4 h within this wave's segment ----
    const int gq = (grp & 7) << 2;
    int gej[5];
    #pragma unroll
    for (int j = 0; j < 5; ++j) gej[j] = ((nl + 4 * j) & 7) << 2;
    const int hs = w * 32;

    float acc[8][5] = {};

    #pragma unroll
    for (int hc = 0; hc < 8; ++hc) {
        const int h = hs + hc * 4;
        float4 qf[8], ef[5];
        #pragma unroll
        for (int i = 0; i < 8; ++i)
            qf[i] = *reinterpret_cast<const float4*>(&u.qs[(grp + 16 * i) * H + (h ^ gq)]);
        #pragma unroll
        for (int j = 0; j < 5; ++j)
            ef[j] = *reinterpret_cast<const float4*>(&es[(nl + 4 * j) * H + (h ^ gej[j])]);
        #pragma unroll
        for (int i = 0; i < 8; ++i)
            #pragma unroll
            for (int j = 0; j < 5; ++j)
                acc[i][j] += fabsf(qf[i].x - ef[j].x) + fabsf(qf[i].y - ef[j].y)
                           + fabsf(qf[i].z - ef[j].z) + fabsf(qf[i].w - ef[j].w);
    }

    // ---- merge the 4 h-segment partials through LDS (aliases qs) ----
    __syncthreads();   // all qs reads done before overwrite
    #pragma unroll
    for (int i = 0; i < 8; ++i)
        #pragma unroll
        for (int j = 0; j < 5; ++j)
            u.red[w][grp + 16 * i][nl + 4 * j] = acc[i][j];
    __syncthreads();

    // ---- epilogue: thread t -> row l = t>>1, n-chunk = (t&1)*10 ----
    {
        const int l  = tid >> 1;
        const int n0 = (tid & 1) * 10;
        float p[10];
        float rs = 0.f;
        #pragma unroll
        for (int k = 0; k < 10; ++k) {
            float d = u.red[0][l][n0 + k] + u.red[1][l][n0 + k]
                    + u.red[2][l][n0 + k] + u.red[3][l][n0 + k];
            p[k] = expf(d);     // no max subtraction: dist <= ~34, f32-safe
            rs += p[k];
        }
        float* po = out + (size_t)l * N_NODES + nb + n0;
        #pragma unroll
        for (int k = 0; k < 5; ++k)
            *reinterpret_cast<float2*>(po + 2 * k) = make_float2(p[2 * k], p[2 * k + 1]);
        rs += __shfl_xor(rs, 1, 64);
        if ((tid & 1) == 0) psum[l * NBLK + blockIdx.x] = rs;
    }
}

// --- kernel C: finish softmax: per-row sum of 500 partials, scale ----------
__global__ __launch_bounds__(256) void k_finish(float* __restrict__ out,
                                                const float* __restrict__ psum) {
    __shared__ float red[4];
    int l = blockIdx.y;
    int tid = threadIdx.x;
    const float* ps = psum + l * NBLK;
    float s = ps[tid] + (tid < NBLK - 256 ? ps[tid + 256] : 0.f);
    #pragma unroll
    for (int m = 1; m < 64; m <<= 1) s += __shfl_xor(s, m, 64);
    if ((tid & 63) == 0) red[tid >> 6] = s;
    __syncthreads();
    float inv = 1.0f / (red[0] + red[1] + red[2] + red[3]);

    int n4 = blockIdx.x * 256 + tid;           // float4 idx within row (<2500)
    if (n4 < 2500) {
        float4* o = reinterpret_cast<float4*>(out) + (size_t)l * 2500 + n4;
        float4 v = *o;
        v.x *= inv; v.y *= inv; v.z *= inv; v.w *= inv;
        *o = v;
    }
}

extern "C" void kernel_launch(void* const* d_in, const int* in_sizes, int n_in,
                              void* d_out, int out_size, void* d_ws, size_t ws_size,
                              hipStream_t stream) {
    const float* node = (const float*)d_in[0];
    const float* rel  = (const float*)d_in[1];
    const int*   eidx = (const int*)d_in[2];
    const int*   ridx = (const int*)d_in[3];
    float* out = (float*)d_out;

    float* query = (float*)d_ws;              // 128*128 = 16384 floats
    float* psum  = (float*)d_ws + 16384;      // 128*500 = 64000 floats

    k_prep<<<32, 256, 0, stream>>>(node, rel, eidx, ridx, query);
    k_main<<<NBLK, 256, 0, stream>>>(node, query, out, psum);

    dim3 gridC((2500 + 255) / 256, L);        // 10 x 128
    k_finish<<<gridC, 256, 0, stream>>>(out, psum);
}